// Round 3
// baseline (393.777 us; speedup 1.0000x reference)
//
#include <hip/hip_runtime.h>
#include <hip/hip_bf16.h>

typedef unsigned short ushort_t;
typedef __attribute__((ext_vector_type(8))) short bf16x8;
typedef __attribute__((ext_vector_type(4))) float f32x4;
typedef __attribute__((ext_vector_type(8))) unsigned short u16x8;
typedef __attribute__((ext_vector_type(4))) unsigned short u16x4;

#define NDIM 2048
#define BDIM 8

__device__ __forceinline__ float bf2f(unsigned short u) {
  union { unsigned int i; float f; } v; v.i = ((unsigned int)u) << 16; return v.f;
}
__device__ __forceinline__ unsigned short f2bf(float f) {
  union { float f; unsigned int i; } v; v.f = f;
  unsigned int x = v.i;
  x += 0x7fffu + ((x >> 16) & 1u);   // round to nearest even
  return (unsigned short)(x >> 16);
}

__device__ __forceinline__ void gload16(const void* g, void* l) {
  __builtin_amdgcn_global_load_lds(
      (const __attribute__((address_space(1))) void*)g,
      (__attribute__((address_space(3))) void*)l,
      16, 0, 0);
}

// ---------- elementwise f32 -> bf16 ----------
__global__ __launch_bounds__(256) void convert_bf16(const float* __restrict__ src,
                                                    unsigned short* __restrict__ dst, int n) {
  int i = (blockIdx.x * 256 + threadIdx.x) * 4;
  if (i < n) {
    f32x4 v = *(const f32x4*)&src[i];
    u16x4 w;
    #pragma unroll
    for (int k = 0; k < 4; ++k) w[k] = f2bf(v[k]);
    *(u16x4*)&dst[i] = w;
  }
}

// ---------- x [b][c][n] f32 -> cur_T [b][n][c] bf16 ----------
__global__ __launch_bounds__(256) void transpose_convert(const float* __restrict__ x,
                                                         unsigned short* __restrict__ dst) {
  __shared__ float tile[64][65];
  const int b  = blockIdx.z;
  const int n0 = blockIdx.x * 64;
  const int c0 = blockIdx.y * 64;
  const int tr = threadIdx.x >> 4;   // 0..15
  const int tc = threadIdx.x & 15;   // 0..15
  const float* src = x + ((size_t)b * NDIM + c0) * NDIM + n0;
  #pragma unroll
  for (int p = 0; p < 4; ++p) {
    int r = p * 16 + tr;
    f32x4 v = *(const f32x4*)&src[(size_t)r * NDIM + tc * 4];
    #pragma unroll
    for (int k = 0; k < 4; ++k) tile[r][tc * 4 + k] = v[k];
  }
  __syncthreads();
  unsigned short* d = dst + ((size_t)b * NDIM + n0) * NDIM + c0;
  #pragma unroll
  for (int p = 0; p < 4; ++p) {
    int r = p * 16 + tr;   // n-local
    u16x4 w;
    #pragma unroll
    for (int k = 0; k < 4; ++k) w[k] = f2bf(tile[tc * 4 + k][r]);
    *(u16x4*)&d[(size_t)r * NDIM + tc * 4] = w;
  }
}

// ---------- wbeff = Wa^T Wb, wceff = Wa^T Wc (two-stage, no atomics) ----------
__global__ __launch_bounds__(256) void weff1(const float* __restrict__ Wa,
                                             const float* __restrict__ Wb,
                                             const float* __restrict__ Wc,
                                             float* __restrict__ part) {
  int c  = blockIdx.x * 256 + threadIdx.x;
  int o0 = blockIdx.y * 128;
  float ab = 0.f, ac = 0.f;
  for (int o = o0; o < o0 + 128; ++o) {
    float w = Wa[(size_t)o * NDIM + c];
    ab = fmaf(Wb[o], w, ab);
    ac = fmaf(Wc[o], w, ac);
  }
  part[(size_t)(blockIdx.y * 2 + 0) * NDIM + c] = ab;
  part[(size_t)(blockIdx.y * 2 + 1) * NDIM + c] = ac;
}
__global__ __launch_bounds__(256) void weff2(const float* __restrict__ part,
                                             float* __restrict__ wbe, float* __restrict__ wce) {
  int c = blockIdx.x * 256 + threadIdx.x;
  float ab = 0.f, ac = 0.f;
  #pragma unroll
  for (int i = 0; i < 16; ++i) {
    ab += part[(size_t)(i * 2 + 0) * NDIM + c];
    ac += part[(size_t)(i * 2 + 1) * NDIM + c];
  }
  wbe[c] = ab; wce[c] = ac;
}

// ---------- t1[b,n] = wbeff . cur_T[b,n,:] + bb ; t2 likewise ----------
__global__ __launch_bounds__(256) void t_kernel(const unsigned short* __restrict__ curT,
                                                const float* __restrict__ wbe,
                                                const float* __restrict__ wce,
                                                const float* __restrict__ bb,
                                                const float* __restrict__ bc,
                                                float* __restrict__ t1, float* __restrict__ t2) {
  int row  = blockIdx.x * 4 + (threadIdx.x >> 6);  // (b,n) flat, one wave per row
  int lane = threadIdx.x & 63;
  const unsigned short* r = curT + (size_t)row * NDIM;
  float a1 = 0.f, a2 = 0.f;
  #pragma unroll
  for (int p = 0; p < 4; ++p) {
    int c0 = p * 512 + lane * 8;
    u16x8 v = *(const u16x8*)&r[c0];
    f32x4 w1a = *(const f32x4*)&wbe[c0];
    f32x4 w1b = *(const f32x4*)&wbe[c0 + 4];
    f32x4 w2a = *(const f32x4*)&wce[c0];
    f32x4 w2b = *(const f32x4*)&wce[c0 + 4];
    #pragma unroll
    for (int j = 0; j < 4; ++j) {
      float xv = bf2f(v[j]);
      a1 = fmaf(w1a[j], xv, a1);
      a2 = fmaf(w2a[j], xv, a2);
    }
    #pragma unroll
    for (int j = 0; j < 4; ++j) {
      float xv = bf2f(v[4 + j]);
      a1 = fmaf(w1b[j], xv, a1);
      a2 = fmaf(w2b[j], xv, a2);
    }
  }
  #pragma unroll
  for (int off = 32; off > 0; off >>= 1) {
    a1 += __shfl_xor(a1, off);
    a2 += __shfl_xor(a2, off);
  }
  if (lane == 0) { t1[row] = a1 + bb[0]; t2[row] = a2 + bc[0]; }
}

// ---------- S[o,n] = log sum_b exp(lrelu(t1[b,n]+t2[b,o])) ----------
__global__ __launch_bounds__(256) void s_kernel(const float* __restrict__ t1,
                                                const float* __restrict__ t2,
                                                float* __restrict__ S) {
  int n = blockIdx.x * 256 + threadIdx.x;
  int o = blockIdx.y;
  float acc = 0.f;
  #pragma unroll
  for (int b = 0; b < BDIM; ++b) {
    float z = t1[b * NDIM + n] + t2[b * NDIM + o];
    z = z >= 0.f ? z : 0.2f * z;
    acc += __expf(z);
  }
  S[(size_t)o * NDIM + n] = __logf(acc);
}

// ---------- fused GEMM + softmax-scale epilogue ----------
// 256x256 tile, BK=32, 8 waves (2M x 4N), ring-4 LDS, ONE barrier window per
// K-tile with counted vmcnt(8); XCD-locality block swizzle (A-pair resident).
__global__ __launch_bounds__(512, 2) void gemm_fused(
    const unsigned short* __restrict__ A,    // Wa bf16 [2048][2048], k-contig
    const unsigned short* __restrict__ Bt,   // cur_T bf16 [8][2048][2048], k-contig
    const float* __restrict__ t1, const float* __restrict__ t2,
    const float* __restrict__ S,  const float* __restrict__ bias,
    unsigned short* __restrict__ outT,       // next cur_T (step 0)
    float* __restrict__ outF,                // d_out (step 1)
    int write_f32) {
  __shared__ __align__(16) unsigned short sbuf[4 * 16384];  // 128 KiB ring-4

  // ---- XCD-locality decode: xcd = id%8 gets bm-pair (id%8)>>1, streams B once.
  const int id   = blockIdx.x;          // 0..511
  const int xcd  = id & 7;
  const int j    = id >> 3;             // 0..63
  const int bm   = (xcd >> 1) * 2 + (j & 1);
  const int idx  = (xcd & 1) * 32 + (j >> 1);
  const int bz   = idx >> 3;
  const int bn   = idx & 7;
  const int bn0  = bn * 256;
  const int bm0  = bm * 256;

  const int tid  = threadIdx.x;
  const int lane = tid & 63;
  const int w    = tid >> 6;           // wave 0..7
  const int wr   = w >> 2;             // 0..1  (M)
  const int wc   = w & 3;              // 0..3  (N)
  const unsigned short* Bb = Bt + (size_t)bz * NDIM * NDIM;

  f32x4 acc[8][4];
  #pragma unroll
  for (int m = 0; m < 8; ++m)
    #pragma unroll
    for (int n = 0; n < 4; ++n) acc[m][n] = (f32x4){0.f, 0.f, 0.f, 0.f};

  // ---- staging decode: wave writes LDS linearly (wave base + lane*16B).
  // LDS row r (64B) slot s' is written by lane (r%16)*4 + s', which loads
  // global slot s'^((r>>1)&3)  (XOR-swizzle, involution).
  const int sr = lane >> 2;            // row within 16-row chunk
  const int sc = lane & 3;             // 16B slot
  const int r0 = (w * 2 + 0) * 16 + sr;
  const int r1 = (w * 2 + 1) * 16 + sr;
  const int sg = sc ^ ((r0 >> 1) & 3);  // rows differ by 16 -> same swizzle bits
  const unsigned short* a0 = A  + (size_t)(bm0 + r0) * NDIM + sg * 8;
  const unsigned short* a1 = A  + (size_t)(bm0 + r1) * NDIM + sg * 8;
  const unsigned short* b0 = Bb + (size_t)(bn0 + r0) * NDIM + sg * 8;
  const unsigned short* b1 = Bb + (size_t)(bn0 + r1) * NDIM + sg * 8;

  auto stageA = [&](int kt, int buf) {
    gload16(a0 + kt, &sbuf[buf * 16384 + (w * 2 + 0) * 512]);
    gload16(a1 + kt, &sbuf[buf * 16384 + (w * 2 + 1) * 512]);
  };
  auto stageB = [&](int kt, int buf) {
    gload16(b0 + kt, &sbuf[buf * 16384 + 8192 + (w * 2 + 0) * 512]);
    gload16(b1 + kt, &sbuf[buf * 16384 + 8192 + (w * 2 + 1) * 512]);
  };

  // ---- fragment-read decode (swizzled): slot' = fs ^ ((fr>>1)&3)
  const int fr = lane & 15;            // fragment row
  const int fs = lane >> 4;            // k-slot 0..3
  const int sp = (fs ^ ((fr >> 1) & 3)) * 8;   // ushort offset within row

  // ---- prologue: stage tiles 0,1,2 ----
  stageA(0, 0);  stageB(0, 0);
  stageA(32, 1); stageB(32, 1);
  stageA(64, 2); stageB(64, 2);
  asm volatile("s_waitcnt vmcnt(8)" ::: "memory");   // tile 0 landed
  __builtin_amdgcn_s_barrier();

  // ---- main loop: 64 K-tiles, ONE barrier window each ----
  for (int t4 = 0; t4 < 64; t4 += 4) {
    #pragma unroll
    for (int u = 0; u < 4; ++u) {
      const int t  = t4 + u;
      const int cb = u;                         // cur buf = t & 3
      const int nb = (u + 3) & 3;               // (t+3) & 3
      const int tc = (t + 3 > 63) ? 63 : (t + 3);   // clamp keeps vmcnt uniform
      const int ktn = tc * 32;
      const unsigned short* Ab = &sbuf[cb * 16384];
      const unsigned short* Bl = &sbuf[cb * 16384 + 8192];

      // issue prefetch first (latency head-start); safe: post-barrier,
      // target buf was last read in window t-1, all waves synced since.
      stageA(ktn, nb);
      stageB(ktn, nb);

      // all 12 fragment reads, in lgkm order av0 -> bv -> av1
      bf16x8 av0[4], bv[4], av1[4];
      #pragma unroll
      for (int m = 0; m < 4; ++m)
        av0[m] = *(const bf16x8*)&Ab[(wr * 128 + m * 16 + fr) * 32 + sp];
      #pragma unroll
      for (int n = 0; n < 4; ++n)
        bv[n] = *(const bf16x8*)&Bl[(wc * 64 + n * 16 + fr) * 32 + sp];
      #pragma unroll
      for (int m = 0; m < 4; ++m)
        av1[m] = *(const bf16x8*)&Ab[(wr * 128 + (m + 4) * 16 + fr) * 32 + sp];

      __builtin_amdgcn_s_setprio(1);
      #pragma unroll
      for (int m = 0; m < 4; ++m)
        #pragma unroll
        for (int n = 0; n < 4; ++n)
          acc[m][n] = __builtin_amdgcn_mfma_f32_16x16x32_bf16(av0[m], bv[n], acc[m][n], 0, 0, 0);
      #pragma unroll
      for (int m = 0; m < 4; ++m)
        #pragma unroll
        for (int n = 0; n < 4; ++n)
          acc[m + 4][n] = __builtin_amdgcn_mfma_f32_16x16x32_bf16(av1[m], bv[n], acc[m + 4][n], 0, 0, 0);
      __builtin_amdgcn_s_setprio(0);

      // counted wait: tiles t+2,t+3 (8 loads) stay in flight; tile t+1 landed
      asm volatile("s_waitcnt vmcnt(8)" ::: "memory");
      __builtin_amdgcn_s_barrier();
    }
  }

  // ---- epilogue ----
  float* sT1f = (float*)&sbuf[0];
  float* sT2f = sT1f + 256;
  if (tid < 256) sT1f[tid] = t1[bz * NDIM + bn0 + tid];
  else           sT2f[tid - 256] = t2[bz * NDIM + bm0 + (tid - 256)];
  __syncthreads();

  const int lr4 = fs * 4;
  #pragma unroll
  for (int m = 0; m < 8; ++m) {
    #pragma unroll
    for (int n = 0; n < 4; ++n) {
      const int oo = wr * 128 + m * 16 + lr4;   // local o of 4 consecutive rows
      const int nn = wc * 64 + n * 16 + fr;     // local n
      const int o  = bm0 + oo;
      const int ng = bn0 + nn;
      const float tz1  = sT1f[nn];
      const float bval = bias[ng];
      if (write_f32) {
        #pragma unroll
        for (int r = 0; r < 4; ++r) {
          float z = tz1 + sT2f[oo + r];
          z = z >= 0.f ? z : 0.2f * z;
          float coef = __expf(z - S[(size_t)(o + r) * NDIM + ng]);
          outF[(size_t)bz * NDIM * NDIM + (size_t)(o + r) * NDIM + ng] =
              fmaf(coef, acc[m][n][r], bval);
        }
      } else {
        u16x4 wv;
        #pragma unroll
        for (int r = 0; r < 4; ++r) {
          float z = tz1 + sT2f[oo + r];
          z = z >= 0.f ? z : 0.2f * z;
          float coef = __expf(z - S[(size_t)(o + r) * NDIM + ng]);
          wv[r] = f2bf(fmaf(coef, acc[m][n][r], bval));
        }
        *(u16x4*)&outT[(size_t)bz * NDIM * NDIM + (size_t)ng * NDIM + o] = wv;
      }
    }
  }
}

extern "C" void kernel_launch(void* const* d_in, const int* in_sizes, int n_in,
                              void* d_out, int out_size, void* d_ws, size_t ws_size,
                              hipStream_t stream) {
  const float* x    = (const float*)d_in[0];
  const float* Wa   = (const float*)d_in[1];
  const float* Wb   = (const float*)d_in[2];
  const float* bb   = (const float*)d_in[3];
  const float* Wc   = (const float*)d_in[4];
  const float* bc   = (const float*)d_in[5];
  const float* bias = (const float*)d_in[6];
  float* out = (float*)d_out;

  char* ws = (char*)d_ws;
  unsigned short* curA = (unsigned short*)ws; ws += (size_t)BDIM * NDIM * NDIM * 2;
  unsigned short* curB = (unsigned short*)ws; ws += (size_t)BDIM * NDIM * NDIM * 2;
  unsigned short* WaB  = (unsigned short*)ws; ws += (size_t)NDIM * NDIM * 2;
  float* t1   = (float*)ws; ws += (size_t)BDIM * NDIM * 4;
  float* t2   = (float*)ws; ws += (size_t)BDIM * NDIM * 4;
  float* wbe  = (float*)ws; ws += NDIM * 4;
  float* wce  = (float*)ws; ws += NDIM * 4;
  float* part = (float*)ws; ws += (size_t)32 * NDIM * 4;
  float* S    = (float*)ws; ws += (size_t)NDIM * NDIM * 4;

  convert_bf16<<<4096, 256, 0, stream>>>(Wa, WaB, NDIM * NDIM);
  transpose_convert<<<dim3(32, 32, BDIM), 256, 0, stream>>>(x, curA);
  weff1<<<dim3(8, 16), 256, 0, stream>>>(Wa, Wb, Wc, part);
  weff2<<<8, 256, 0, stream>>>(part, wbe, wce);

  for (int step = 0; step < 2; ++step) {
    const unsigned short* cur = step ? curB : curA;
    t_kernel<<<(BDIM * NDIM) / 4, 256, 0, stream>>>(cur, wbe, wce, bb, bc, t1, t2);
    s_kernel<<<dim3(NDIM / 256, NDIM), 256, 0, stream>>>(t1, t2, S);
    gemm_fused<<<512, 512, 0, stream>>>(
        WaB, cur, t1, t2, S, bias, curB, out, step);
  }
}

// Round 4
// 388.844 us; speedup vs baseline: 1.0127x; 1.0127x over previous
//
#include <hip/hip_runtime.h>
#include <hip/hip_bf16.h>

typedef unsigned short ushort_t;
typedef __attribute__((ext_vector_type(8))) short bf16x8;
typedef __attribute__((ext_vector_type(4))) float f32x4;
typedef __attribute__((ext_vector_type(8))) unsigned short u16x8;
typedef __attribute__((ext_vector_type(4))) unsigned short u16x4;

#define NDIM 2048
#define BDIM 8

__device__ __forceinline__ float bf2f(unsigned short u) {
  union { unsigned int i; float f; } v; v.i = ((unsigned int)u) << 16; return v.f;
}
__device__ __forceinline__ unsigned short f2bf(float f) {
  union { float f; unsigned int i; } v; v.f = f;
  unsigned int x = v.i;
  x += 0x7fffu + ((x >> 16) & 1u);   // round to nearest even
  return (unsigned short)(x >> 16);
}

__device__ __forceinline__ void gload16(const void* g, void* l) {
  __builtin_amdgcn_global_load_lds(
      (const __attribute__((address_space(1))) void*)g,
      (__attribute__((address_space(3))) void*)l,
      16, 0, 0);
}

// ---------- elementwise f32 -> bf16 ----------
__global__ __launch_bounds__(256) void convert_bf16(const float* __restrict__ src,
                                                    unsigned short* __restrict__ dst, int n) {
  int i = (blockIdx.x * 256 + threadIdx.x) * 4;
  if (i < n) {
    f32x4 v = *(const f32x4*)&src[i];
    u16x4 w;
    #pragma unroll
    for (int k = 0; k < 4; ++k) w[k] = f2bf(v[k]);
    *(u16x4*)&dst[i] = w;
  }
}

// ---------- x [b][c][n] f32 -> cur_T [b][n][c] bf16 ----------
__global__ __launch_bounds__(256) void transpose_convert(const float* __restrict__ x,
                                                         unsigned short* __restrict__ dst) {
  __shared__ float tile[64][65];
  const int b  = blockIdx.z;
  const int n0 = blockIdx.x * 64;
  const int c0 = blockIdx.y * 64;
  const int tr = threadIdx.x >> 4;   // 0..15
  const int tc = threadIdx.x & 15;   // 0..15
  const float* src = x + ((size_t)b * NDIM + c0) * NDIM + n0;
  #pragma unroll
  for (int p = 0; p < 4; ++p) {
    int r = p * 16 + tr;
    f32x4 v = *(const f32x4*)&src[(size_t)r * NDIM + tc * 4];
    #pragma unroll
    for (int k = 0; k < 4; ++k) tile[r][tc * 4 + k] = v[k];
  }
  __syncthreads();
  unsigned short* d = dst + ((size_t)b * NDIM + n0) * NDIM + c0;
  #pragma unroll
  for (int p = 0; p < 4; ++p) {
    int r = p * 16 + tr;   // n-local
    u16x4 w;
    #pragma unroll
    for (int k = 0; k < 4; ++k) w[k] = f2bf(tile[tc * 4 + k][r]);
    *(u16x4*)&d[(size_t)r * NDIM + tc * 4] = w;
  }
}

// ---------- wbeff = Wa^T Wb, wceff = Wa^T Wc (two-stage, no atomics) ----------
__global__ __launch_bounds__(256) void weff1(const float* __restrict__ Wa,
                                             const float* __restrict__ Wb,
                                             const float* __restrict__ Wc,
                                             float* __restrict__ part) {
  int c  = blockIdx.x * 256 + threadIdx.x;
  int o0 = blockIdx.y * 128;
  float ab = 0.f, ac = 0.f;
  for (int o = o0; o < o0 + 128; ++o) {
    float w = Wa[(size_t)o * NDIM + c];
    ab = fmaf(Wb[o], w, ab);
    ac = fmaf(Wc[o], w, ac);
  }
  part[(size_t)(blockIdx.y * 2 + 0) * NDIM + c] = ab;
  part[(size_t)(blockIdx.y * 2 + 1) * NDIM + c] = ac;
}
__global__ __launch_bounds__(256) void weff2(const float* __restrict__ part,
                                             float* __restrict__ wbe, float* __restrict__ wce) {
  int c = blockIdx.x * 256 + threadIdx.x;
  float ab = 0.f, ac = 0.f;
  #pragma unroll
  for (int i = 0; i < 16; ++i) {
    ab += part[(size_t)(i * 2 + 0) * NDIM + c];
    ac += part[(size_t)(i * 2 + 1) * NDIM + c];
  }
  wbe[c] = ab; wce[c] = ac;
}

// ---------- t1[b,n] = wbeff . cur_T[b,n,:] + bb ; t2 likewise ----------
__global__ __launch_bounds__(256) void t_kernel(const unsigned short* __restrict__ curT,
                                                const float* __restrict__ wbe,
                                                const float* __restrict__ wce,
                                                const float* __restrict__ bb,
                                                const float* __restrict__ bc,
                                                float* __restrict__ t1, float* __restrict__ t2) {
  int row  = blockIdx.x * 4 + (threadIdx.x >> 6);  // (b,n) flat, one wave per row
  int lane = threadIdx.x & 63;
  const unsigned short* r = curT + (size_t)row * NDIM;
  float a1 = 0.f, a2 = 0.f;
  #pragma unroll
  for (int p = 0; p < 4; ++p) {
    int c0 = p * 512 + lane * 8;
    u16x8 v = *(const u16x8*)&r[c0];
    f32x4 w1a = *(const f32x4*)&wbe[c0];
    f32x4 w1b = *(const f32x4*)&wbe[c0 + 4];
    f32x4 w2a = *(const f32x4*)&wce[c0];
    f32x4 w2b = *(const f32x4*)&wce[c0 + 4];
    #pragma unroll
    for (int j = 0; j < 4; ++j) {
      float xv = bf2f(v[j]);
      a1 = fmaf(w1a[j], xv, a1);
      a2 = fmaf(w2a[j], xv, a2);
    }
    #pragma unroll
    for (int j = 0; j < 4; ++j) {
      float xv = bf2f(v[4 + j]);
      a1 = fmaf(w1b[j], xv, a1);
      a2 = fmaf(w2b[j], xv, a2);
    }
  }
  #pragma unroll
  for (int off = 32; off > 0; off >>= 1) {
    a1 += __shfl_xor(a1, off);
    a2 += __shfl_xor(a2, off);
  }
  if (lane == 0) { t1[row] = a1 + bb[0]; t2[row] = a2 + bc[0]; }
}

// ---------- S[o,n] = log sum_b exp(lrelu(t1[b,n]+t2[b,o])) ----------
__global__ __launch_bounds__(256) void s_kernel(const float* __restrict__ t1,
                                                const float* __restrict__ t2,
                                                float* __restrict__ S) {
  int n = blockIdx.x * 256 + threadIdx.x;
  int o = blockIdx.y;
  float acc = 0.f;
  #pragma unroll
  for (int b = 0; b < BDIM; ++b) {
    float z = t1[b * NDIM + n] + t2[b * NDIM + o];
    z = z >= 0.f ? z : 0.2f * z;
    acc += __expf(z);
  }
  S[(size_t)o * NDIM + n] = __logf(acc);
}

// ---------- fused GEMM + softmax-scale epilogue ----------
// 256x256 tile, BK=32, 8 waves (2M x 4N), ring-4 LDS, two pinned phases per
// K-tile (m201 discipline: reads+stage | sched_barrier | s_barrier | lgkmcnt(0)
// | sched_barrier | MFMA burst | s_barrier), counted vmcnt(8) once per K-tile.
__global__ __launch_bounds__(512, 2) void gemm_fused(
    const unsigned short* __restrict__ A,    // Wa bf16 [2048][2048], k-contig
    const unsigned short* __restrict__ Bt,   // cur_T bf16 [8][2048][2048], k-contig
    const float* __restrict__ t1, const float* __restrict__ t2,
    const float* __restrict__ S,  const float* __restrict__ bias,
    unsigned short* __restrict__ outT,       // next cur_T (step 0)
    float* __restrict__ outF,                // d_out (step 1)
    int write_f32) {
  __shared__ __align__(16) unsigned short sbuf[4 * 16384];  // 128 KiB ring-4

  const int tid  = threadIdx.x;
  const int lane = tid & 63;
  const int w    = tid >> 6;           // wave 0..7
  const int wr   = w >> 2;             // 0..1  (M)
  const int wc   = w & 3;              // 0..3  (N)
  const int bn0  = blockIdx.x * 256;   // x fastest -> id%8 = bn -> one bn per XCD
  const int bm0  = blockIdx.y * 256;
  const int bz   = blockIdx.z;
  const unsigned short* Bb = Bt + (size_t)bz * NDIM * NDIM;

  f32x4 acc[8][4];
  #pragma unroll
  for (int m = 0; m < 8; ++m)
    #pragma unroll
    for (int n = 0; n < 4; ++n) acc[m][n] = (f32x4){0.f, 0.f, 0.f, 0.f};

  // ---- staging decode: wave writes LDS linearly (wave base + lane*16B).
  // LDS row r (64B) slot s' is written by lane (r%16)*4 + s', which loads
  // global slot s'^((r>>1)&3)  (XOR-swizzle, involution).
  const int sr = lane >> 2;            // row within 16-row chunk
  const int sc = lane & 3;             // 16B slot
  const int r0 = (w * 2 + 0) * 16 + sr;
  const int r1 = (w * 2 + 1) * 16 + sr;
  const int sg = sc ^ ((r0 >> 1) & 3);  // rows differ by 16 -> same swizzle bits
  const unsigned short* a0 = A  + (size_t)(bm0 + r0) * NDIM + sg * 8;
  const unsigned short* a1 = A  + (size_t)(bm0 + r1) * NDIM + sg * 8;
  const unsigned short* b0 = Bb + (size_t)(bn0 + r0) * NDIM + sg * 8;
  const unsigned short* b1 = Bb + (size_t)(bn0 + r1) * NDIM + sg * 8;

  auto stageA = [&](int kt, int buf) {
    gload16(a0 + kt, &sbuf[buf * 16384 + (w * 2 + 0) * 512]);
    gload16(a1 + kt, &sbuf[buf * 16384 + (w * 2 + 1) * 512]);
  };
  auto stageB = [&](int kt, int buf) {
    gload16(b0 + kt, &sbuf[buf * 16384 + 8192 + (w * 2 + 0) * 512]);
    gload16(b1 + kt, &sbuf[buf * 16384 + 8192 + (w * 2 + 1) * 512]);
  };

  // ---- fragment-read decode (swizzled): slot' = fs ^ ((fr>>1)&3)
  const int fr = lane & 15;            // fragment row
  const int fs = lane >> 4;            // k-slot 0..3
  const int sp = (fs ^ ((fr >> 1) & 3)) * 8;   // ushort offset within row

  // ---- prologue: stage tiles 0,1,2 ----
  stageA(0, 0);  stageB(0, 0);
  stageA(32, 1); stageB(32, 1);
  stageA(64, 2); stageB(64, 2);
  asm volatile("s_waitcnt vmcnt(8)" ::: "memory");   // tile 0 landed
  __builtin_amdgcn_s_barrier();

  // ---- main loop: 64 K-tiles, two pinned phases each ----
  for (int t4 = 0; t4 < 64; t4 += 4) {
    #pragma unroll
    for (int u = 0; u < 4; ++u) {
      const int t  = t4 + u;
      const int cb = u;                         // cur buf = t & 3
      const int nb = (u + 3) & 3;               // (t+3) & 3
      const int tc = (t + 3 > 63) ? 63 : (t + 3);   // clamp keeps vmcnt uniform
      const int ktn = tc * 32;
      const unsigned short* Ab = &sbuf[cb * 16384];
      const unsigned short* Bl = &sbuf[cb * 16384 + 8192];

      bf16x8 av[4], bv[4];
      // ======== phase A: read av(m0-3)+bv, stage A(t+3), MFMA m0-3 ========
      #pragma unroll
      for (int m = 0; m < 4; ++m)
        av[m] = *(const bf16x8*)&Ab[(wr * 128 + m * 16 + fr) * 32 + sp];
      #pragma unroll
      for (int n = 0; n < 4; ++n)
        bv[n] = *(const bf16x8*)&Bl[(wc * 64 + n * 16 + fr) * 32 + sp];
      stageA(ktn, nb);
      __builtin_amdgcn_sched_barrier(0);       // pin: reads+stage stay above
      __builtin_amdgcn_s_barrier();
      asm volatile("s_waitcnt lgkmcnt(0)" ::: "memory");
      __builtin_amdgcn_sched_barrier(0);       // rule #18: MFMA must not hoist
      __builtin_amdgcn_s_setprio(1);
      #pragma unroll
      for (int m = 0; m < 4; ++m)
        #pragma unroll
        for (int n = 0; n < 4; ++n)
          acc[m][n] = __builtin_amdgcn_mfma_f32_16x16x32_bf16(av[m], bv[n], acc[m][n], 0, 0, 0);
      __builtin_amdgcn_s_setprio(0);
      __builtin_amdgcn_sched_barrier(0);       // pin: MFMA burst stays here
      __builtin_amdgcn_s_barrier();

      // ======== phase B: read av(m4-7), stage B(t+3), MFMA m4-7 ========
      #pragma unroll
      for (int m = 0; m < 4; ++m)
        av[m] = *(const bf16x8*)&Ab[(wr * 128 + (m + 4) * 16 + fr) * 32 + sp];
      stageB(ktn, nb);
      __builtin_amdgcn_sched_barrier(0);
      __builtin_amdgcn_s_barrier();
      asm volatile("s_waitcnt lgkmcnt(0)" ::: "memory");
      __builtin_amdgcn_sched_barrier(0);
      __builtin_amdgcn_s_setprio(1);
      #pragma unroll
      for (int m = 0; m < 4; ++m)
        #pragma unroll
        for (int n = 0; n < 4; ++n)
          acc[m + 4][n] = __builtin_amdgcn_mfma_f32_16x16x32_bf16(av[m], bv[n], acc[m + 4][n], 0, 0, 0);
      __builtin_amdgcn_s_setprio(0);
      __builtin_amdgcn_sched_barrier(0);
      // counted wait: tiles t+2,t+3 (8 loads) stay in flight; tile t+1 landed
      asm volatile("s_waitcnt vmcnt(8)" ::: "memory");
      __builtin_amdgcn_s_barrier();
    }
  }

  // ---- epilogue ----
  float* sT1f = (float*)&sbuf[0];
  float* sT2f = sT1f + 256;
  if (tid < 256) sT1f[tid] = t1[bz * NDIM + bn0 + tid];
  else           sT2f[tid - 256] = t2[bz * NDIM + bm0 + (tid - 256)];
  __syncthreads();

  const int lr4 = fs * 4;
  #pragma unroll
  for (int m = 0; m < 8; ++m) {
    #pragma unroll
    for (int n = 0; n < 4; ++n) {
      const int oo = wr * 128 + m * 16 + lr4;   // local o of 4 consecutive rows
      const int nn = wc * 64 + n * 16 + fr;     // local n
      const int o  = bm0 + oo;
      const int ng = bn0 + nn;
      const float tz1  = sT1f[nn];
      const float bval = bias[ng];
      if (write_f32) {
        #pragma unroll
        for (int r = 0; r < 4; ++r) {
          float z = tz1 + sT2f[oo + r];
          z = z >= 0.f ? z : 0.2f * z;
          float coef = __expf(z - S[(size_t)(o + r) * NDIM + ng]);
          outF[(size_t)bz * NDIM * NDIM + (size_t)(o + r) * NDIM + ng] =
              fmaf(coef, acc[m][n][r], bval);
        }
      } else {
        u16x4 wv;
        #pragma unroll
        for (int r = 0; r < 4; ++r) {
          float z = tz1 + sT2f[oo + r];
          z = z >= 0.f ? z : 0.2f * z;
          float coef = __expf(z - S[(size_t)(o + r) * NDIM + ng]);
          wv[r] = f2bf(fmaf(coef, acc[m][n][r], bval));
        }
        *(u16x4*)&outT[(size_t)bz * NDIM * NDIM + (size_t)ng * NDIM + o] = wv;
      }
    }
  }
}

extern "C" void kernel_launch(void* const* d_in, const int* in_sizes, int n_in,
                              void* d_out, int out_size, void* d_ws, size_t ws_size,
                              hipStream_t stream) {
  const float* x    = (const float*)d_in[0];
  const float* Wa   = (const float*)d_in[1];
  const float* Wb   = (const float*)d_in[2];
  const float* bb   = (const float*)d_in[3];
  const float* Wc   = (const float*)d_in[4];
  const float* bc   = (const float*)d_in[5];
  const float* bias = (const float*)d_in[6];
  float* out = (float*)d_out;

  char* ws = (char*)d_ws;
  unsigned short* curA = (unsigned short*)ws; ws += (size_t)BDIM * NDIM * NDIM * 2;
  unsigned short* curB = (unsigned short*)ws; ws += (size_t)BDIM * NDIM * NDIM * 2;
  unsigned short* WaB  = (unsigned short*)ws; ws += (size_t)NDIM * NDIM * 2;
  float* t1   = (float*)ws; ws += (size_t)BDIM * NDIM * 4;
  float* t2   = (float*)ws; ws += (size_t)BDIM * NDIM * 4;
  float* wbe  = (float*)ws; ws += NDIM * 4;
  float* wce  = (float*)ws; ws += NDIM * 4;
  float* part = (float*)ws; ws += (size_t)32 * NDIM * 4;
  float* S    = (float*)ws; ws += (size_t)NDIM * NDIM * 4;

  convert_bf16<<<4096, 256, 0, stream>>>(Wa, WaB, NDIM * NDIM);
  transpose_convert<<<dim3(32, 32, BDIM), 256, 0, stream>>>(x, curA);
  weff1<<<dim3(8, 16), 256, 0, stream>>>(Wa, Wb, Wc, part);
  weff2<<<8, 256, 0, stream>>>(part, wbe, wce);

  for (int step = 0; step < 2; ++step) {
    const unsigned short* cur = step ? curB : curA;
    t_kernel<<<(BDIM * NDIM) / 4, 256, 0, stream>>>(cur, wbe, wce, bb, bc, t1, t2);
    s_kernel<<<dim3(NDIM / 256, NDIM), 256, 0, stream>>>(t1, t2, S);
    gemm_fused<<<dim3(8, 8, BDIM), 512, 0, stream>>>(
        WaB, cur, t1, t2, S, bias, curB, out, step);
  }
}

// Round 5
// 386.956 us; speedup vs baseline: 1.0176x; 1.0049x over previous
//
#include <hip/hip_runtime.h>
#include <hip/hip_bf16.h>

typedef unsigned short ushort_t;
typedef __attribute__((ext_vector_type(8))) short bf16x8;
typedef __attribute__((ext_vector_type(4))) float f32x4;
typedef __attribute__((ext_vector_type(8))) unsigned short u16x8;
typedef __attribute__((ext_vector_type(4))) unsigned short u16x4;

#define NDIM 2048
#define BDIM 8

__device__ __forceinline__ float bf2f(unsigned short u) {
  union { unsigned int i; float f; } v; v.i = ((unsigned int)u) << 16; return v.f;
}
__device__ __forceinline__ unsigned short f2bf(float f) {
  union { float f; unsigned int i; } v; v.f = f;
  unsigned int x = v.i;
  x += 0x7fffu + ((x >> 16) & 1u);   // round to nearest even
  return (unsigned short)(x >> 16);
}

__device__ __forceinline__ void gload16(const void* g, void* l) {
  __builtin_amdgcn_global_load_lds(
      (const __attribute__((address_space(1))) void*)g,
      (__attribute__((address_space(3))) void*)l,
      16, 0, 0);
}

// ---------- elementwise f32 -> bf16 ----------
__global__ __launch_bounds__(256) void convert_bf16(const float* __restrict__ src,
                                                    unsigned short* __restrict__ dst, int n) {
  int i = (blockIdx.x * 256 + threadIdx.x) * 4;
  if (i < n) {
    f32x4 v = *(const f32x4*)&src[i];
    u16x4 w;
    #pragma unroll
    for (int k = 0; k < 4; ++k) w[k] = f2bf(v[k]);
    *(u16x4*)&dst[i] = w;
  }
}

// ---------- x [b][c][n] f32 -> cur_T [b][n][c] bf16 ----------
__global__ __launch_bounds__(256) void transpose_convert(const float* __restrict__ x,
                                                         unsigned short* __restrict__ dst) {
  __shared__ float tile[64][65];
  const int b  = blockIdx.z;
  const int n0 = blockIdx.x * 64;
  const int c0 = blockIdx.y * 64;
  const int tr = threadIdx.x >> 4;   // 0..15
  const int tc = threadIdx.x & 15;   // 0..15
  const float* src = x + ((size_t)b * NDIM + c0) * NDIM + n0;
  #pragma unroll
  for (int p = 0; p < 4; ++p) {
    int r = p * 16 + tr;
    f32x4 v = *(const f32x4*)&src[(size_t)r * NDIM + tc * 4];
    #pragma unroll
    for (int k = 0; k < 4; ++k) tile[r][tc * 4 + k] = v[k];
  }
  __syncthreads();
  unsigned short* d = dst + ((size_t)b * NDIM + n0) * NDIM + c0;
  #pragma unroll
  for (int p = 0; p < 4; ++p) {
    int r = p * 16 + tr;   // n-local
    u16x4 w;
    #pragma unroll
    for (int k = 0; k < 4; ++k) w[k] = f2bf(tile[tc * 4 + k][r]);
    *(u16x4*)&d[(size_t)r * NDIM + tc * 4] = w;
  }
}

// ---------- wbeff = Wa^T Wb, wceff = Wa^T Wc (two-stage, no atomics) ----------
__global__ __launch_bounds__(256) void weff1(const float* __restrict__ Wa,
                                             const float* __restrict__ Wb,
                                             const float* __restrict__ Wc,
                                             float* __restrict__ part) {
  int c  = blockIdx.x * 256 + threadIdx.x;
  int o0 = blockIdx.y * 128;
  float ab = 0.f, ac = 0.f;
  for (int o = o0; o < o0 + 128; ++o) {
    float w = Wa[(size_t)o * NDIM + c];
    ab = fmaf(Wb[o], w, ab);
    ac = fmaf(Wc[o], w, ac);
  }
  part[(size_t)(blockIdx.y * 2 + 0) * NDIM + c] = ab;
  part[(size_t)(blockIdx.y * 2 + 1) * NDIM + c] = ac;
}
__global__ __launch_bounds__(256) void weff2(const float* __restrict__ part,
                                             float* __restrict__ wbe, float* __restrict__ wce) {
  int c = blockIdx.x * 256 + threadIdx.x;
  float ab = 0.f, ac = 0.f;
  #pragma unroll
  for (int i = 0; i < 16; ++i) {
    ab += part[(size_t)(i * 2 + 0) * NDIM + c];
    ac += part[(size_t)(i * 2 + 1) * NDIM + c];
  }
  wbe[c] = ab; wce[c] = ac;
}

// ---------- t1[b,n] = wbeff . cur_T[b,n,:] + bb ; t2 likewise ----------
__global__ __launch_bounds__(256) void t_kernel(const unsigned short* __restrict__ curT,
                                                const float* __restrict__ wbe,
                                                const float* __restrict__ wce,
                                                const float* __restrict__ bb,
                                                const float* __restrict__ bc,
                                                float* __restrict__ t1, float* __restrict__ t2) {
  int row  = blockIdx.x * 4 + (threadIdx.x >> 6);  // (b,n) flat, one wave per row
  int lane = threadIdx.x & 63;
  const unsigned short* r = curT + (size_t)row * NDIM;
  float a1 = 0.f, a2 = 0.f;
  #pragma unroll
  for (int p = 0; p < 4; ++p) {
    int c0 = p * 512 + lane * 8;
    u16x8 v = *(const u16x8*)&r[c0];
    f32x4 w1a = *(const f32x4*)&wbe[c0];
    f32x4 w1b = *(const f32x4*)&wbe[c0 + 4];
    f32x4 w2a = *(const f32x4*)&wce[c0];
    f32x4 w2b = *(const f32x4*)&wce[c0 + 4];
    #pragma unroll
    for (int j = 0; j < 4; ++j) {
      float xv = bf2f(v[j]);
      a1 = fmaf(w1a[j], xv, a1);
      a2 = fmaf(w2a[j], xv, a2);
    }
    #pragma unroll
    for (int j = 0; j < 4; ++j) {
      float xv = bf2f(v[4 + j]);
      a1 = fmaf(w1b[j], xv, a1);
      a2 = fmaf(w2b[j], xv, a2);
    }
  }
  #pragma unroll
  for (int off = 32; off > 0; off >>= 1) {
    a1 += __shfl_xor(a1, off);
    a2 += __shfl_xor(a2, off);
  }
  if (lane == 0) { t1[row] = a1 + bb[0]; t2[row] = a2 + bc[0]; }
}

// ---------- S[o,n] = log sum_b exp(lrelu(t1[b,n]+t2[b,o])) ----------
__global__ __launch_bounds__(256) void s_kernel(const float* __restrict__ t1,
                                                const float* __restrict__ t2,
                                                float* __restrict__ S) {
  int n = blockIdx.x * 256 + threadIdx.x;
  int o = blockIdx.y;
  float acc = 0.f;
  #pragma unroll
  for (int b = 0; b < BDIM; ++b) {
    float z = t1[b * NDIM + n] + t2[b * NDIM + o];
    z = z >= 0.f ? z : 0.2f * z;
    acc += __expf(z);
  }
  S[(size_t)o * NDIM + n] = __logf(acc);
}

// ---------- fused GEMM + softmax-scale epilogue ----------
// 256x256 tile, BK=32, 8 waves (2M x 4N), ring-4 LDS, ONE barrier per K-tile.
// All 12 ds_reads issue up front (two fenced groups); lgkmcnt(4) lets the av1
// reads drain under MFMA burst 0; counted vmcnt(8) keeps 2 tiles in flight.
__global__ __launch_bounds__(512, 2) void gemm_fused(
    const unsigned short* __restrict__ A,    // Wa bf16 [2048][2048], k-contig
    const unsigned short* __restrict__ Bt,   // cur_T bf16 [8][2048][2048], k-contig
    const float* __restrict__ t1, const float* __restrict__ t2,
    const float* __restrict__ S,  const float* __restrict__ bias,
    unsigned short* __restrict__ outT,       // next cur_T (step 0)
    float* __restrict__ outF,                // d_out (step 1)
    int write_f32) {
  __shared__ __align__(16) unsigned short sbuf[4 * 16384];  // 128 KiB ring-4

  const int tid  = threadIdx.x;
  const int lane = tid & 63;
  const int w    = tid >> 6;           // wave 0..7
  const int wr   = w >> 2;             // 0..1  (M)
  const int wc   = w & 3;              // 0..3  (N)
  const int bn0  = blockIdx.x * 256;   // x fastest -> id%8 = bn -> one bn per XCD
  const int bm0  = blockIdx.y * 256;
  const int bz   = blockIdx.z;
  const unsigned short* Bb = Bt + (size_t)bz * NDIM * NDIM;

  f32x4 acc[8][4];
  #pragma unroll
  for (int m = 0; m < 8; ++m)
    #pragma unroll
    for (int n = 0; n < 4; ++n) acc[m][n] = (f32x4){0.f, 0.f, 0.f, 0.f};

  // ---- staging decode: wave writes LDS linearly (wave base + lane*16B).
  // LDS row r (64B) slot s' is written by lane (r%16)*4 + s', which loads
  // global slot s'^((r>>1)&3)  (XOR-swizzle, involution).
  const int sr = lane >> 2;            // row within 16-row chunk
  const int sc = lane & 3;             // 16B slot
  const int r0 = (w * 2 + 0) * 16 + sr;
  const int r1 = (w * 2 + 1) * 16 + sr;
  const int sg = sc ^ ((r0 >> 1) & 3);  // rows differ by 16 -> same swizzle bits
  const unsigned short* a0 = A  + (size_t)(bm0 + r0) * NDIM + sg * 8;
  const unsigned short* a1 = A  + (size_t)(bm0 + r1) * NDIM + sg * 8;
  const unsigned short* b0 = Bb + (size_t)(bn0 + r0) * NDIM + sg * 8;
  const unsigned short* b1 = Bb + (size_t)(bn0 + r1) * NDIM + sg * 8;

  auto stageA = [&](int kt, int buf) {
    gload16(a0 + kt, &sbuf[buf * 16384 + (w * 2 + 0) * 512]);
    gload16(a1 + kt, &sbuf[buf * 16384 + (w * 2 + 1) * 512]);
  };
  auto stageB = [&](int kt, int buf) {
    gload16(b0 + kt, &sbuf[buf * 16384 + 8192 + (w * 2 + 0) * 512]);
    gload16(b1 + kt, &sbuf[buf * 16384 + 8192 + (w * 2 + 1) * 512]);
  };

  // ---- fragment-read decode (swizzled): slot' = fs ^ ((fr>>1)&3)
  const int fr = lane & 15;            // fragment row
  const int fs = lane >> 4;            // k-slot 0..3
  const int sp = (fs ^ ((fr >> 1) & 3)) * 8;   // ushort offset within row

  // ---- prologue: stage tiles 0,1,2 ----
  stageA(0, 0);  stageB(0, 0);
  stageA(32, 1); stageB(32, 1);
  stageA(64, 2); stageB(64, 2);
  asm volatile("s_waitcnt vmcnt(8)" ::: "memory");   // tile 0 landed
  __builtin_amdgcn_s_barrier();

  // ---- main loop: 64 K-tiles, ONE barrier window each ----
  for (int t4 = 0; t4 < 64; t4 += 4) {
    #pragma unroll
    for (int u = 0; u < 4; ++u) {
      const int t  = t4 + u;
      const int cb = u;                         // cur buf = t & 3
      const int nb = (u + 3) & 3;               // (t+3) & 3
      const int tc = (t + 3 > 63) ? 63 : (t + 3);   // clamp keeps vmcnt uniform
      const int ktn = tc * 32;
      const unsigned short* Ab = &sbuf[cb * 16384];
      const unsigned short* Bl = &sbuf[cb * 16384 + 8192];

      // prefetch tile t+3 (safe: buf nb last read in window t-1, barrier since)
      stageA(ktn, nb);
      stageB(ktn, nb);

      bf16x8 av0[4], bv[4], av1[4];
      // group 1: av0 + bv (8 reads)
      #pragma unroll
      for (int m = 0; m < 4; ++m)
        av0[m] = *(const bf16x8*)&Ab[(wr * 128 + m * 16 + fr) * 32 + sp];
      #pragma unroll
      for (int n = 0; n < 4; ++n)
        bv[n] = *(const bf16x8*)&Bl[(wc * 64 + n * 16 + fr) * 32 + sp];
      __builtin_amdgcn_sched_barrier(0);   // group 1 issues before group 2
      // group 2: av1 (4 reads) — drains under MFMA burst 0
      #pragma unroll
      for (int m = 0; m < 4; ++m)
        av1[m] = *(const bf16x8*)&Ab[(wr * 128 + (m + 4) * 16 + fr) * 32 + sp];
      __builtin_amdgcn_sched_barrier(0);

      asm volatile("s_waitcnt lgkmcnt(4)" ::: "memory");   // av0+bv ready
      __builtin_amdgcn_sched_barrier(0);   // rule #18: MFMA must not hoist
      __builtin_amdgcn_s_setprio(1);
      #pragma unroll
      for (int m = 0; m < 4; ++m)
        #pragma unroll
        for (int n = 0; n < 4; ++n)
          acc[m][n] = __builtin_amdgcn_mfma_f32_16x16x32_bf16(av0[m], bv[n], acc[m][n], 0, 0, 0);
      __builtin_amdgcn_s_setprio(0);
      __builtin_amdgcn_sched_barrier(0);

      asm volatile("s_waitcnt lgkmcnt(0)" ::: "memory");   // av1 ready
      __builtin_amdgcn_sched_barrier(0);
      __builtin_amdgcn_s_setprio(1);
      #pragma unroll
      for (int m = 0; m < 4; ++m)
        #pragma unroll
        for (int n = 0; n < 4; ++n)
          acc[m + 4][n] = __builtin_amdgcn_mfma_f32_16x16x32_bf16(av1[m], bv[n], acc[m + 4][n], 0, 0, 0);
      __builtin_amdgcn_s_setprio(0);
      __builtin_amdgcn_sched_barrier(0);

      // counted wait: tiles t+2,t+3 (8 loads) stay in flight; tile t+1 landed
      asm volatile("s_waitcnt vmcnt(8)" ::: "memory");
      __builtin_amdgcn_s_barrier();
    }
  }

  // ---- epilogue ----
  float* sT1f = (float*)&sbuf[0];
  float* sT2f = sT1f + 256;
  if (tid < 256) sT1f[tid] = t1[bz * NDIM + bn0 + tid];
  else           sT2f[tid - 256] = t2[bz * NDIM + bm0 + (tid - 256)];
  __syncthreads();

  const int lr4 = fs * 4;
  #pragma unroll
  for (int m = 0; m < 8; ++m) {
    #pragma unroll
    for (int n = 0; n < 4; ++n) {
      const int oo = wr * 128 + m * 16 + lr4;   // local o of 4 consecutive rows
      const int nn = wc * 64 + n * 16 + fr;     // local n
      const int o  = bm0 + oo;
      const int ng = bn0 + nn;
      const float tz1  = sT1f[nn];
      const float bval = bias[ng];
      if (write_f32) {
        #pragma unroll
        for (int r = 0; r < 4; ++r) {
          float z = tz1 + sT2f[oo + r];
          z = z >= 0.f ? z : 0.2f * z;
          float coef = __expf(z - S[(size_t)(o + r) * NDIM + ng]);
          outF[(size_t)bz * NDIM * NDIM + (size_t)(o + r) * NDIM + ng] =
              fmaf(coef, acc[m][n][r], bval);
        }
      } else {
        u16x4 wv;
        #pragma unroll
        for (int r = 0; r < 4; ++r) {
          float z = tz1 + sT2f[oo + r];
          z = z >= 0.f ? z : 0.2f * z;
          float coef = __expf(z - S[(size_t)(o + r) * NDIM + ng]);
          wv[r] = f2bf(fmaf(coef, acc[m][n][r], bval));
        }
        *(u16x4*)&outT[(size_t)bz * NDIM * NDIM + (size_t)ng * NDIM + o] = wv;
      }
    }
  }
}

extern "C" void kernel_launch(void* const* d_in, const int* in_sizes, int n_in,
                              void* d_out, int out_size, void* d_ws, size_t ws_size,
                              hipStream_t stream) {
  const float* x    = (const float*)d_in[0];
  const float* Wa   = (const float*)d_in[1];
  const float* Wb   = (const float*)d_in[2];
  const float* bb   = (const float*)d_in[3];
  const float* Wc   = (const float*)d_in[4];
  const float* bc   = (const float*)d_in[5];
  const float* bias = (const float*)d_in[6];
  float* out = (float*)d_out;

  char* ws = (char*)d_ws;
  unsigned short* curA = (unsigned short*)ws; ws += (size_t)BDIM * NDIM * NDIM * 2;
  unsigned short* curB = (unsigned short*)ws; ws += (size_t)BDIM * NDIM * NDIM * 2;
  unsigned short* WaB  = (unsigned short*)ws; ws += (size_t)NDIM * NDIM * 2;
  float* t1   = (float*)ws; ws += (size_t)BDIM * NDIM * 4;
  float* t2   = (float*)ws; ws += (size_t)BDIM * NDIM * 4;
  float* wbe  = (float*)ws; ws += NDIM * 4;
  float* wce  = (float*)ws; ws += NDIM * 4;
  float* part = (float*)ws; ws += (size_t)32 * NDIM * 4;
  float* S    = (float*)ws; ws += (size_t)NDIM * NDIM * 4;

  convert_bf16<<<4096, 256, 0, stream>>>(Wa, WaB, NDIM * NDIM);
  transpose_convert<<<dim3(32, 32, BDIM), 256, 0, stream>>>(x, curA);
  weff1<<<dim3(8, 16), 256, 0, stream>>>(Wa, Wb, Wc, part);
  weff2<<<8, 256, 0, stream>>>(part, wbe, wce);

  for (int step = 0; step < 2; ++step) {
    const unsigned short* cur = step ? curB : curA;
    t_kernel<<<(BDIM * NDIM) / 4, 256, 0, stream>>>(cur, wbe, wce, bb, bc, t1, t2);
    s_kernel<<<dim3(NDIM / 256, NDIM), 256, 0, stream>>>(t1, t2, S);
    gemm_fused<<<dim3(8, 8, BDIM), 512, 0, stream>>>(
        WaB, cur, t1, t2, S, bias, curB, out, step);
  }
}